// Round 8
// baseline (522.057 us; speedup 1.0000x reference)
//
#include <hip/hip_runtime.h>

// HGIN_classifier: two relational-GIN layers (R=2), ReLU between.
// R8: fuse aggregate INTO gemm (row-local!): block stages x rows + gathers
// neighbor sums directly into LDS (aggh never hits global — kills 102 MB of
// ws round-trip), then barrier-free MFMA K-loop with A from LDS, B from L2.
// 3 blocks/CU -> gather phase of one block overlaps MFMA phase of another.
// Pipeline: zero_small -> bucketA -> bscan -> bucketB -> bucketC (CSR build)
//           cvt_x, cvt_w -> gemm_fused (agg+GEMM+L2-transform) -> gather2

typedef _Float16 f16;
typedef _Float16 f16x2 __attribute__((ext_vector_type(2)));
typedef _Float16 f16x4 __attribute__((ext_vector_type(4)));
typedef _Float16 f16x8 __attribute__((ext_vector_type(8)));
typedef float    f32x4 __attribute__((ext_vector_type(4)));

constexpr int NN   = 100000;
constexpr int NR   = NN * 2;     // (node, relation) segments
constexpr int NB   = 512;        // coarse buckets
constexpr int BSH  = 9;          // bucket = seg >> BSH (512 segs/bucket)
constexpr int CHUNK = 8192;      // edges per block in bucketA/B
constexpr int APAD = 392;        // Ash row stride in halfs (784 B: 2-way-free)

__global__ void zero_small(int* __restrict__ gcnt) {
  int t = threadIdx.x;
  if (t < NB) gcnt[t] = 0;
}

__global__ void bucketA(const int* __restrict__ dst, const int* __restrict__ et,
                        int* __restrict__ gcnt, int E) {
  __shared__ int h[NB];
  int t = threadIdx.x;
  for (int b = t; b < NB; b += 256) h[b] = 0;
  __syncthreads();
  int lo = blockIdx.x * CHUNK, hi = min(E, lo + CHUNK);
  for (int e = lo + t; e < hi; e += 256)
    atomicAdd(&h[(dst[e] * 2 + et[e]) >> BSH], 1);
  __syncthreads();
  for (int b = t; b < NB; b += 256) {
    int c = h[b];
    if (c) atomicAdd(&gcnt[b], c);
  }
}

__global__ void bscan(const int* __restrict__ gcnt, int* __restrict__ bstart,
                      int* __restrict__ gbase) {  // 1 block, 512 threads
  __shared__ int s[NB];
  int t = threadIdx.x;
  int v = gcnt[t];
  s[t] = v;
  __syncthreads();
  #pragma unroll
  for (int o = 1; o < NB; o <<= 1) {
    int u = (t >= o) ? s[t - o] : 0;
    __syncthreads();
    s[t] += u;
    __syncthreads();
  }
  bstart[t] = s[t] - v;
  gbase[t]  = s[t] - v;
  if (t == NB - 1) bstart[NB] = s[t];
}

__global__ void bucketB(const int* __restrict__ src, const int* __restrict__ dst,
                        const int* __restrict__ et, int* __restrict__ gbase,
                        int2* __restrict__ ebuf, int E) {
  __shared__ int h[NB], base[NB];
  int t = threadIdx.x;
  for (int b = t; b < NB; b += 256) h[b] = 0;
  __syncthreads();
  int lo = blockIdx.x * CHUNK, hi = min(E, lo + CHUNK);
  for (int e = lo + t; e < hi; e += 256)
    atomicAdd(&h[(dst[e] * 2 + et[e]) >> BSH], 1);
  __syncthreads();
  for (int b = t; b < NB; b += 256) {
    int c = h[b];
    base[b] = c ? atomicAdd(&gbase[b], c) : 0;
    h[b] = 0;
  }
  __syncthreads();
  for (int e = lo + t; e < hi; e += 256) {
    int seg = dst[e] * 2 + et[e];
    int b = seg >> BSH;
    int r = atomicAdd(&h[b], 1);
    ebuf[base[b] + r] = make_int2(src[e], seg);
  }
}

// One block per bucket: build CSR off for its 512 segs + dense srcs scatter.
__global__ void bucketC(const int2* __restrict__ ebuf, const int* __restrict__ bstart,
                        int* __restrict__ off, int* __restrict__ srcs) {
  __shared__ int sh[NB], soff[NB], cnt[NB], tmp[256];
  int b = blockIdx.x, t = threadIdx.x;
  int lo = bstart[b], hi = bstart[b + 1];
  for (int s0 = t; s0 < NB; s0 += 256) { sh[s0] = 0; cnt[s0] = 0; }
  __syncthreads();
  for (int e = lo + t; e < hi; e += 256)
    atomicAdd(&sh[ebuf[e].y - (b << BSH)], 1);
  __syncthreads();
  int a0 = sh[2 * t], a1 = sh[2 * t + 1];
  tmp[t] = a0 + a1;
  __syncthreads();
  #pragma unroll
  for (int o = 1; o < 256; o <<= 1) {
    int u = (t >= o) ? tmp[t - o] : 0;
    __syncthreads();
    tmp[t] += u;
    __syncthreads();
  }
  int ex = tmp[t] - (a0 + a1);
  soff[2 * t] = ex;
  soff[2 * t + 1] = ex + a0;
  __syncthreads();
  int g0 = (b << BSH) + 2 * t;
  if (g0 <= NR)     off[g0]     = lo + soff[2 * t];
  if (g0 + 1 <= NR) off[g0 + 1] = lo + soff[2 * t + 1];
  for (int e = lo + t; e < hi; e += 256) {
    int2 p = ebuf[e];
    int s = p.y - (b << BSH);
    int r = atomicAdd(&cnt[s], 1);
    srcs[lo + soff[s] + r] = p.x;
  }
}

__global__ void cvt_x(const float4* __restrict__ xf, f16* __restrict__ xh, int n4) {
  int i = blockIdx.x * blockDim.x + threadIdx.x;
  if (i >= n4) return;
  float4 v = xf[i];
  f16x4 h;
  h.x = (f16)v.x; h.y = (f16)v.y; h.z = (f16)v.z; h.w = (f16)v.w;
  *(f16x4*)(xh + (size_t)i * 4) = h;
}

// k-step-major repack: w1t[ks][n][ki] = f16(W[ks*32+ki][n]).
__global__ void cvt_w(const float* __restrict__ w1s, const float* __restrict__ w1r,
                      f16* __restrict__ w1t) {
  int id = blockIdx.x * blockDim.x + threadIdx.x;
  if (id >= 12 * 256 * 32) return;
  int ks = id >> 13, rem = id & 8191;
  int n = rem >> 5, ki = rem & 31;
  int k = ks * 32 + ki;
  float v = (k < 128) ? w1s[k * 256 + n] : w1r[(k - 128) * 256 + n];
  w1t[id] = (f16)v;
}

// Fused: neighbor aggregation (into LDS) + layer-1 f16 MFMA GEMM + fused
// layer-2 transform epilogue. Block = 64 rows; Ash row r = [x[r] (128h) |
// agg0[r] (128h) | agg1[r] (128h)] padded to APAD=392 halfs.
// Phase 2 wave wv: rows 0..63 x cols [wv*64,+64); acc 4x4 f32x4 = 64 VGPR.
// Fragment layouts (m89/m120-verified): A: m=lane&15, k=quad*8+j;
// B: n=lane&15, k=quad*8+j; C/D: col=lane&15, row=quad*4+reg.
__global__ __launch_bounds__(256) void gemm_fused(
    const f16* __restrict__ xh, const int* __restrict__ off,
    const int* __restrict__ srcs, const f16* __restrict__ w1t,
    const float* __restrict__ b1, const float* __restrict__ w2s,
    const float* __restrict__ w2r, const float* __restrict__ b2,
    float* __restrict__ z2, float* __restrict__ out) {
  __shared__ __align__(16) f16 Ash[64 * APAD];        // 50176 B
  float (*zbuf)[64][6] = (float (*)[64][6])(void*)Ash; // aliased (6144 B)
  const int t = threadIdx.x;
  const int lane = t & 63, wv = t >> 6;
  const int ml = lane & 15, quad = lane >> 4;
  const long rowBase = (long)blockIdx.x * 64;

  // ---- phase 1a: stage x rows into Ash cols [0,128)
  #pragma unroll
  for (int j = 0; j < 4; ++j) {
    int chunkId = t * 4 + j;            // 0..1023
    int r = chunkId >> 4, c = chunkId & 15;
    long grow = rowBase + r;
    uint4 v = make_uint4(0, 0, 0, 0);
    if (grow < NN) v = *(const uint4*)(xh + grow * 128 + c * 8);
    *(uint4*)&Ash[r * APAD + c * 8] = v;
  }

  // ---- phase 1b: gather-aggregate into Ash cols [128,384). 1 wave/node,
  // lane l owns cols 2l,2l+1; 4 nodes in flight per pass, 16 passes/wave.
  for (int w = wv; w < 64; w += 4) {
    long node = rowBase + w;
    float a0 = 0.f, a1 = 0.f, c0 = 0.f, c1 = 0.f;
    if (node < NN) {
      int e0 = off[2 * node], e1 = off[2 * node + 1], e2 = off[2 * node + 2];
      int e = e0;
      for (; e + 3 < e1; e += 4) {
        int s0 = srcs[e], s1 = srcs[e + 1], s2 = srcs[e + 2], s3 = srcs[e + 3];
        f16x2 v0 = *(const f16x2*)(xh + (long)s0 * 128 + lane * 2);
        f16x2 v1 = *(const f16x2*)(xh + (long)s1 * 128 + lane * 2);
        f16x2 v2 = *(const f16x2*)(xh + (long)s2 * 128 + lane * 2);
        f16x2 v3 = *(const f16x2*)(xh + (long)s3 * 128 + lane * 2);
        a0 += (float)v0.x + (float)v1.x + (float)v2.x + (float)v3.x;
        a1 += (float)v0.y + (float)v1.y + (float)v2.y + (float)v3.y;
      }
      for (; e < e1; ++e) {
        f16x2 v = *(const f16x2*)(xh + (long)srcs[e] * 128 + lane * 2);
        a0 += (float)v.x; a1 += (float)v.y;
      }
      e = e1;
      for (; e + 3 < e2; e += 4) {
        int s0 = srcs[e], s1 = srcs[e + 1], s2 = srcs[e + 2], s3 = srcs[e + 3];
        f16x2 v0 = *(const f16x2*)(xh + (long)s0 * 128 + lane * 2);
        f16x2 v1 = *(const f16x2*)(xh + (long)s1 * 128 + lane * 2);
        f16x2 v2 = *(const f16x2*)(xh + (long)s2 * 128 + lane * 2);
        f16x2 v3 = *(const f16x2*)(xh + (long)s3 * 128 + lane * 2);
        c0 += (float)v0.x + (float)v1.x + (float)v2.x + (float)v3.x;
        c1 += (float)v0.y + (float)v1.y + (float)v2.y + (float)v3.y;
      }
      for (; e < e2; ++e) {
        f16x2 v = *(const f16x2*)(xh + (long)srcs[e] * 128 + lane * 2);
        c0 += (float)v.x; c1 += (float)v.y;
      }
    }
    f16x2 o0; o0.x = (f16)a0; o0.y = (f16)a1;
    f16x2 o1; o1.x = (f16)c0; o1.y = (f16)c1;
    *(f16x2*)&Ash[w * APAD + 128 + lane * 2] = o0;
    *(f16x2*)&Ash[w * APAD + 256 + lane * 2] = o1;
  }
  __syncthreads();

  // ---- phase 2: barrier-free K-loop. A from LDS, B direct from L2.
  const f16* bbase = w1t + (long)(wv * 64 + ml) * 32 + quad * 8;
  f32x4 acc[4][4];
  #pragma unroll
  for (int mt = 0; mt < 4; ++mt)
    #pragma unroll
    for (int nt = 0; nt < 4; ++nt) acc[mt][nt] = (f32x4)(0.f);

  #pragma unroll
  for (int ks = 0; ks < 12; ++ks) {
    f16x8 af[4], bf[4];
    #pragma unroll
    for (int mt = 0; mt < 4; ++mt)
      af[mt] = *(const f16x8*)&Ash[(mt * 16 + ml) * APAD + ks * 32 + quad * 8];
    #pragma unroll
    for (int nt = 0; nt < 4; ++nt)
      bf[nt] = *(const f16x8*)(bbase + (long)ks * 8192 + nt * 16 * 32);
    #pragma unroll
    for (int mt = 0; mt < 4; ++mt)
      #pragma unroll
      for (int nt = 0; nt < 4; ++nt)
        acc[mt][nt] = __builtin_amdgcn_mfma_f32_16x16x32_f16(af[mt], bf[nt],
                                                             acc[mt][nt], 0, 0, 0);
  }
  __syncthreads();   // all Ash reads done before zbuf (aliased) writes

  // Epilogue: h = relu(acc + b1[col]); 6 dots over this wave's 64 cols;
  // reduce over the 16 ml-lanes; partials to zbuf[wv].
  #pragma unroll
  for (int mt = 0; mt < 4; ++mt) {
    float z[4][6];
    #pragma unroll
    for (int rr = 0; rr < 4; ++rr)
      #pragma unroll
      for (int p = 0; p < 6; ++p) z[rr][p] = 0.f;
    #pragma unroll
    for (int nt = 0; nt < 4; ++nt) {
      int col = wv * 64 + nt * 16 + ml;
      float bb = b1[col];
      float wA = w2r[col * 2 + 0];
      float wB = w2r[col * 2 + 1];
      float wC = w2r[512 + col * 2 + 0];
      float wD = w2r[512 + col * 2 + 1];
      float wE = w2s[col * 2 + 0];
      float wF = w2s[col * 2 + 1];
      #pragma unroll
      for (int rr = 0; rr < 4; ++rr) {
        float h = acc[mt][nt][rr] + bb;
        h = h > 0.f ? h : 0.f;
        z[rr][0] = fmaf(h, wA, z[rr][0]);
        z[rr][1] = fmaf(h, wB, z[rr][1]);
        z[rr][2] = fmaf(h, wC, z[rr][2]);
        z[rr][3] = fmaf(h, wD, z[rr][3]);
        z[rr][4] = fmaf(h, wE, z[rr][4]);
        z[rr][5] = fmaf(h, wF, z[rr][5]);
      }
    }
    #pragma unroll
    for (int rr = 0; rr < 4; ++rr)
      #pragma unroll
      for (int p = 0; p < 6; ++p) {
        float v = z[rr][p];
        v += __shfl_xor(v, 1);
        v += __shfl_xor(v, 2);
        v += __shfl_xor(v, 4);
        v += __shfl_xor(v, 8);
        if (ml == 0) zbuf[wv][mt * 16 + quad * 4 + rr][p] = v;
      }
  }
  __syncthreads();
  for (int i = t; i < 384; i += 256) {
    int r = i / 6, p = i % 6;
    long grow = rowBase + r;
    if (grow < NN) {
      float v = zbuf[0][r][p] + zbuf[1][r][p] + zbuf[2][r][p] + zbuf[3][r][p];
      if (p < 4) z2[grow * 4 + p] = v;
      else       out[grow * 2 + (p - 4)] = v + b2[p - 4];
    }
  }
}

// 4 lanes per node: lane sub handles every-4th edge; reduce over sub.
__global__ void gather2(const float* __restrict__ z2, const int* __restrict__ off,
                        const int* __restrict__ srcs, float* __restrict__ out) {
  int tid = blockIdx.x * blockDim.x + threadIdx.x;
  int n = tid >> 2;
  if (n >= NN) return;
  int sub = tid & 3;
  int e0 = off[2 * n];
  int e1 = off[2 * n + 1];
  int e2 = off[2 * n + 2];
  float o0 = 0.f, o1 = 0.f;
  for (int e = e0 + sub; e < e1; e += 4) {
    float2 v = *(const float2*)(z2 + (long)srcs[e] * 4);
    o0 += v.x; o1 += v.y;
  }
  for (int e = e1 + sub; e < e2; e += 4) {
    float2 v = *(const float2*)(z2 + (long)srcs[e] * 4 + 2);
    o0 += v.x; o1 += v.y;
  }
  o0 += __shfl_xor(o0, 1); o1 += __shfl_xor(o1, 1);
  o0 += __shfl_xor(o0, 2); o1 += __shfl_xor(o1, 2);
  if (sub == 0) {
    out[n * 2 + 0] += o0;
    out[n * 2 + 1] += o1;
  }
}

extern "C" void kernel_launch(void* const* d_in, const int* in_sizes, int n_in,
                              void* d_out, int out_size, void* d_ws, size_t ws_size,
                              hipStream_t stream) {
  const float* x   = (const float*)d_in[0];
  const int*   ei  = (const int*)d_in[1];
  const int*   et  = (const int*)d_in[2];
  const float* w1s = (const float*)d_in[3];
  const float* w1r = (const float*)d_in[4];
  const float* b1  = (const float*)d_in[5];
  const float* w2s = (const float*)d_in[6];
  const float* w2r = (const float*)d_in[7];
  const float* b2  = (const float*)d_in[8];
  float* out = (float*)d_out;
  const int E = in_sizes[2];
  const int* src = ei;
  const int* dst = ei + E;

  f16*   xh   = (f16*)d_ws;                      // NN*128 f16   (25.6 MB)
  f16*   w1t  = xh + (size_t)NN * 128;           // 12*256*32 f16 (0.2 MB)
  float* z2   = (float*)(w1t + 12 * 256 * 32);   // NN*4 f32     (1.6 MB)
  int2*  ebuf = (int2*)(z2 + (size_t)NN * 4);    // E int2       (12.8 MB)
  int*   srcs = (int*)(ebuf + E);                // E int        (6.4 MB)
  int*   off  = srcs + E;                        // NR+1 int     (0.8 MB)
  int*   gcnt = off + NR + 1;                    // NB int
  int*   bstart = gcnt + NB;                     // NB+1 int
  int*   gbase  = bstart + NB + 1;               // NB int

  int nblk = (E + CHUNK - 1) / CHUNK;
  zero_small<<<1, 512, 0, stream>>>(gcnt);
  bucketA<<<nblk, 256, 0, stream>>>(dst, et, gcnt, E);
  bscan<<<1, 512, 0, stream>>>(gcnt, bstart, gbase);
  bucketB<<<nblk, 256, 0, stream>>>(src, dst, et, gbase, ebuf, E);
  bucketC<<<NB, 256, 0, stream>>>(ebuf, bstart, off, srcs);

  int n4 = NN * 128 / 4;
  cvt_x<<<(n4 + 255) / 256, 256, 0, stream>>>((const float4*)x, xh, n4);
  cvt_w<<<(12 * 256 * 32 + 255) / 256, 256, 0, stream>>>(w1s, w1r, w1t);

  gemm_fused<<<(NN + 63) / 64, 256, 0, stream>>>(xh, off, srcs, w1t,
                                                 b1, w2s, w2r, b2, z2, out);

  gather2<<<(NN * 4 + 255) / 256, 256, 0, stream>>>(z2, off, srcs, out);
}

// Round 9
// 405.514 us; speedup vs baseline: 1.2874x; 1.2874x over previous
//
#include <hip/hip_runtime.h>

// HGIN_classifier: two relational-GIN layers (R=2), ReLU between.
// R9: revert R8 fusion (gather needs max wave-parallelism: 32 tiny waves/CU,
// not 12 waves stuck behind a block barrier). R7 split structure plus:
//  - gemm: explicit depth-1 prefetch rotation (R7's 88-VGPR schedule had no
//    load/compute distance -> latency-serialized at MfmaUtil 6%)
//  - aggregate: edge-loop unroll 8 (8 outstanding 256B row gathers/wave)
// Pipeline: zero_small -> bucketA -> bscan -> bucketB -> bucketC (CSR build)
//           cvt_x, cvt_w -> aggregate -> gemm_mfma -> gather2

typedef _Float16 f16;
typedef _Float16 f16x2 __attribute__((ext_vector_type(2)));
typedef _Float16 f16x4 __attribute__((ext_vector_type(4)));
typedef _Float16 f16x8 __attribute__((ext_vector_type(8)));
typedef float    f32x4 __attribute__((ext_vector_type(4)));

constexpr int NN   = 100000;
constexpr int NR   = NN * 2;     // (node, relation) segments
constexpr int NB   = 512;        // coarse buckets
constexpr int BSH  = 9;          // bucket = seg >> BSH (512 segs/bucket)
constexpr int CHUNK = 8192;      // edges per block in bucketA/B

__global__ void zero_small(int* __restrict__ gcnt) {
  int t = threadIdx.x;
  if (t < NB) gcnt[t] = 0;
}

__global__ void bucketA(const int* __restrict__ dst, const int* __restrict__ et,
                        int* __restrict__ gcnt, int E) {
  __shared__ int h[NB];
  int t = threadIdx.x;
  for (int b = t; b < NB; b += 256) h[b] = 0;
  __syncthreads();
  int lo = blockIdx.x * CHUNK, hi = min(E, lo + CHUNK);
  for (int e = lo + t; e < hi; e += 256)
    atomicAdd(&h[(dst[e] * 2 + et[e]) >> BSH], 1);
  __syncthreads();
  for (int b = t; b < NB; b += 256) {
    int c = h[b];
    if (c) atomicAdd(&gcnt[b], c);
  }
}

__global__ void bscan(const int* __restrict__ gcnt, int* __restrict__ bstart,
                      int* __restrict__ gbase) {  // 1 block, 512 threads
  __shared__ int s[NB];
  int t = threadIdx.x;
  int v = gcnt[t];
  s[t] = v;
  __syncthreads();
  #pragma unroll
  for (int o = 1; o < NB; o <<= 1) {
    int u = (t >= o) ? s[t - o] : 0;
    __syncthreads();
    s[t] += u;
    __syncthreads();
  }
  bstart[t] = s[t] - v;
  gbase[t]  = s[t] - v;
  if (t == NB - 1) bstart[NB] = s[t];
}

__global__ void bucketB(const int* __restrict__ src, const int* __restrict__ dst,
                        const int* __restrict__ et, int* __restrict__ gbase,
                        int2* __restrict__ ebuf, int E) {
  __shared__ int h[NB], base[NB];
  int t = threadIdx.x;
  for (int b = t; b < NB; b += 256) h[b] = 0;
  __syncthreads();
  int lo = blockIdx.x * CHUNK, hi = min(E, lo + CHUNK);
  for (int e = lo + t; e < hi; e += 256)
    atomicAdd(&h[(dst[e] * 2 + et[e]) >> BSH], 1);
  __syncthreads();
  for (int b = t; b < NB; b += 256) {
    int c = h[b];
    base[b] = c ? atomicAdd(&gbase[b], c) : 0;
    h[b] = 0;
  }
  __syncthreads();
  for (int e = lo + t; e < hi; e += 256) {
    int seg = dst[e] * 2 + et[e];
    int b = seg >> BSH;
    int r = atomicAdd(&h[b], 1);
    ebuf[base[b] + r] = make_int2(src[e], seg);
  }
}

// One block per bucket: build CSR off for its 512 segs + dense srcs scatter.
__global__ void bucketC(const int2* __restrict__ ebuf, const int* __restrict__ bstart,
                        int* __restrict__ off, int* __restrict__ srcs) {
  __shared__ int sh[NB], soff[NB], cnt[NB], tmp[256];
  int b = blockIdx.x, t = threadIdx.x;
  int lo = bstart[b], hi = bstart[b + 1];
  for (int s0 = t; s0 < NB; s0 += 256) { sh[s0] = 0; cnt[s0] = 0; }
  __syncthreads();
  for (int e = lo + t; e < hi; e += 256)
    atomicAdd(&sh[ebuf[e].y - (b << BSH)], 1);
  __syncthreads();
  int a0 = sh[2 * t], a1 = sh[2 * t + 1];
  tmp[t] = a0 + a1;
  __syncthreads();
  #pragma unroll
  for (int o = 1; o < 256; o <<= 1) {
    int u = (t >= o) ? tmp[t - o] : 0;
    __syncthreads();
    tmp[t] += u;
    __syncthreads();
  }
  int ex = tmp[t] - (a0 + a1);
  soff[2 * t] = ex;
  soff[2 * t + 1] = ex + a0;
  __syncthreads();
  int g0 = (b << BSH) + 2 * t;
  if (g0 <= NR)     off[g0]     = lo + soff[2 * t];
  if (g0 + 1 <= NR) off[g0 + 1] = lo + soff[2 * t + 1];
  for (int e = lo + t; e < hi; e += 256) {
    int2 p = ebuf[e];
    int s = p.y - (b << BSH);
    int r = atomicAdd(&cnt[s], 1);
    srcs[lo + soff[s] + r] = p.x;
  }
}

__global__ void cvt_x(const float4* __restrict__ xf, f16* __restrict__ xh, int n4) {
  int i = blockIdx.x * blockDim.x + threadIdx.x;
  if (i >= n4) return;
  float4 v = xf[i];
  f16x4 h;
  h.x = (f16)v.x; h.y = (f16)v.y; h.z = (f16)v.z; h.w = (f16)v.w;
  *(f16x4*)(xh + (size_t)i * 4) = h;
}

// k-step-major repack: w1t[ks][n][ki] = f16(W[ks*32+ki][n]).
__global__ void cvt_w(const float* __restrict__ w1s, const float* __restrict__ w1r,
                      f16* __restrict__ w1t) {
  int id = blockIdx.x * blockDim.x + threadIdx.x;
  if (id >= 12 * 256 * 32) return;
  int ks = id >> 13, rem = id & 8191;
  int n = rem >> 5, ki = rem & 31;
  int k = ks * 32 + ki;
  float v = (k < 128) ? w1s[k * 256 + n] : w1r[(k - 128) * 256 + n];
  w1t[id] = (f16)v;
}

// One wave per node; lane l owns cols 2l,2l+1; unroll x8 for MLP.
__global__ void aggregate(const f16* __restrict__ xh, const int* __restrict__ off,
                          const int* __restrict__ srcs, f16* __restrict__ aggh) {
  int w = (blockIdx.x * blockDim.x + threadIdx.x) >> 6;
  if (w >= NN) return;
  int lane = threadIdx.x & 63;
  int e0 = off[2 * w];
  int e1 = off[2 * w + 1];
  int e2 = off[2 * w + 2];
  float a0 = 0.f, a1 = 0.f, c0 = 0.f, c1 = 0.f;
  int e = e0;
  for (; e + 7 < e1; e += 8) {
    f16x2 v0 = *(const f16x2*)(xh + (long)srcs[e]     * 128 + lane * 2);
    f16x2 v1 = *(const f16x2*)(xh + (long)srcs[e + 1] * 128 + lane * 2);
    f16x2 v2 = *(const f16x2*)(xh + (long)srcs[e + 2] * 128 + lane * 2);
    f16x2 v3 = *(const f16x2*)(xh + (long)srcs[e + 3] * 128 + lane * 2);
    f16x2 v4 = *(const f16x2*)(xh + (long)srcs[e + 4] * 128 + lane * 2);
    f16x2 v5 = *(const f16x2*)(xh + (long)srcs[e + 5] * 128 + lane * 2);
    f16x2 v6 = *(const f16x2*)(xh + (long)srcs[e + 6] * 128 + lane * 2);
    f16x2 v7 = *(const f16x2*)(xh + (long)srcs[e + 7] * 128 + lane * 2);
    a0 += (float)v0.x + (float)v1.x + (float)v2.x + (float)v3.x
        + (float)v4.x + (float)v5.x + (float)v6.x + (float)v7.x;
    a1 += (float)v0.y + (float)v1.y + (float)v2.y + (float)v3.y
        + (float)v4.y + (float)v5.y + (float)v6.y + (float)v7.y;
  }
  for (; e < e1; ++e) {
    f16x2 v = *(const f16x2*)(xh + (long)srcs[e] * 128 + lane * 2);
    a0 += (float)v.x; a1 += (float)v.y;
  }
  e = e1;
  for (; e + 7 < e2; e += 8) {
    f16x2 v0 = *(const f16x2*)(xh + (long)srcs[e]     * 128 + lane * 2);
    f16x2 v1 = *(const f16x2*)(xh + (long)srcs[e + 1] * 128 + lane * 2);
    f16x2 v2 = *(const f16x2*)(xh + (long)srcs[e + 2] * 128 + lane * 2);
    f16x2 v3 = *(const f16x2*)(xh + (long)srcs[e + 3] * 128 + lane * 2);
    f16x2 v4 = *(const f16x2*)(xh + (long)srcs[e + 4] * 128 + lane * 2);
    f16x2 v5 = *(const f16x2*)(xh + (long)srcs[e + 5] * 128 + lane * 2);
    f16x2 v6 = *(const f16x2*)(xh + (long)srcs[e + 6] * 128 + lane * 2);
    f16x2 v7 = *(const f16x2*)(xh + (long)srcs[e + 7] * 128 + lane * 2);
    c0 += (float)v0.x + (float)v1.x + (float)v2.x + (float)v3.x
        + (float)v4.x + (float)v5.x + (float)v6.x + (float)v7.x;
    c1 += (float)v0.y + (float)v1.y + (float)v2.y + (float)v3.y
        + (float)v4.y + (float)v5.y + (float)v6.y + (float)v7.y;
  }
  for (; e < e2; ++e) {
    f16x2 v = *(const f16x2*)(xh + (long)srcs[e] * 128 + lane * 2);
    c0 += (float)v.x; c1 += (float)v.y;
  }
  f16* row = aggh + (long)w * 256;
  f16x2 o0; o0.x = (f16)a0; o0.y = (f16)a1;
  f16x2 o1; o1.x = (f16)c0; o1.y = (f16)c1;
  *(f16x2*)(row + lane * 2) = o0;
  *(f16x2*)(row + 128 + lane * 2) = o1;
}

// Fused layer-1 GEMM (f16 MFMA) + layer-2 transform epilogue. Barrier-free,
// direct-global A/B, with explicit depth-1 prefetch rotation so each ks's
// loads issue before ks-1's MFMAs retire. Block 256 thr = 4 waves; wave wv
// covers rows [blk*64,+64) x cols [wv*64,+64): acc 4x4 f32x4 = 64 VGPR.
// Fragment layouts (m89/m120-verified): A: m=lane&15, k=quad*8+j;
// B: n=lane&15, k=quad*8+j; C/D: col=lane&15, row=quad*4+reg.
__global__ __launch_bounds__(256) void gemm_mfma(
    const f16* __restrict__ xh, const f16* __restrict__ aggh,
    const f16* __restrict__ w1t,
    const float* __restrict__ b1, const float* __restrict__ w2s,
    const float* __restrict__ w2r, const float* __restrict__ b2,
    float* __restrict__ z2, float* __restrict__ out) {
  __shared__ float zbuf[4][64][6];
  const int t = threadIdx.x;
  const int lane = t & 63, wv = t >> 6;
  const int ml = lane & 15, quad = lane >> 4;
  const long rowBase = (long)blockIdx.x * 64;

  long rowc[4];
  #pragma unroll
  for (int mt = 0; mt < 4; ++mt) {
    long r = rowBase + mt * 16 + ml;
    rowc[mt] = r < NN ? r : (NN - 1);   // tail block clamps; writes masked
  }
  const f16* bbase = w1t + (long)(wv * 64 + ml) * 32 + quad * 8;

  f32x4 acc[4][4];
  #pragma unroll
  for (int mt = 0; mt < 4; ++mt)
    #pragma unroll
    for (int nt = 0; nt < 4; ++nt) acc[mt][nt] = (f32x4)(0.f);

  auto loadA = [&](int ks, int mt) -> f16x8 {
    const f16* ap = (ks < 4)
        ? (xh + rowc[mt] * 128 + ks * 32 + quad * 8)
        : (aggh + rowc[mt] * 256 + (ks - 4) * 32 + quad * 8);
    return *(const f16x8*)ap;
  };

  f16x8 afc[4], bfc[4], afn[4], bfn[4];
  #pragma unroll
  for (int mt = 0; mt < 4; ++mt) afc[mt] = loadA(0, mt);
  #pragma unroll
  for (int nt = 0; nt < 4; ++nt)
    bfc[nt] = *(const f16x8*)(bbase + nt * 16 * 32);

  #pragma unroll
  for (int ks = 0; ks < 12; ++ks) {
    if (ks < 11) {
      #pragma unroll
      for (int mt = 0; mt < 4; ++mt) afn[mt] = loadA(ks + 1, mt);
      #pragma unroll
      for (int nt = 0; nt < 4; ++nt)
        bfn[nt] = *(const f16x8*)(bbase + (long)(ks + 1) * 8192 + nt * 16 * 32);
    }
    #pragma unroll
    for (int mt = 0; mt < 4; ++mt)
      #pragma unroll
      for (int nt = 0; nt < 4; ++nt)
        acc[mt][nt] = __builtin_amdgcn_mfma_f32_16x16x32_f16(afc[mt], bfc[nt],
                                                             acc[mt][nt], 0, 0, 0);
    #pragma unroll
    for (int i = 0; i < 4; ++i) { afc[i] = afn[i]; bfc[i] = bfn[i]; }
  }

  // Epilogue: h = relu(acc + b1[col]); 6 dots over this wave's 64 cols;
  // reduce over the 16 ml-lanes; partials to zbuf[wv].
  #pragma unroll
  for (int mt = 0; mt < 4; ++mt) {
    float z[4][6];
    #pragma unroll
    for (int rr = 0; rr < 4; ++rr)
      #pragma unroll
      for (int p = 0; p < 6; ++p) z[rr][p] = 0.f;
    #pragma unroll
    for (int nt = 0; nt < 4; ++nt) {
      int col = wv * 64 + nt * 16 + ml;
      float bb = b1[col];
      float wA = w2r[col * 2 + 0];
      float wB = w2r[col * 2 + 1];
      float wC = w2r[512 + col * 2 + 0];
      float wD = w2r[512 + col * 2 + 1];
      float wE = w2s[col * 2 + 0];
      float wF = w2s[col * 2 + 1];
      #pragma unroll
      for (int rr = 0; rr < 4; ++rr) {
        float h = acc[mt][nt][rr] + bb;
        h = h > 0.f ? h : 0.f;
        z[rr][0] = fmaf(h, wA, z[rr][0]);
        z[rr][1] = fmaf(h, wB, z[rr][1]);
        z[rr][2] = fmaf(h, wC, z[rr][2]);
        z[rr][3] = fmaf(h, wD, z[rr][3]);
        z[rr][4] = fmaf(h, wE, z[rr][4]);
        z[rr][5] = fmaf(h, wF, z[rr][5]);
      }
    }
    #pragma unroll
    for (int rr = 0; rr < 4; ++rr)
      #pragma unroll
      for (int p = 0; p < 6; ++p) {
        float v = z[rr][p];
        v += __shfl_xor(v, 1);
        v += __shfl_xor(v, 2);
        v += __shfl_xor(v, 4);
        v += __shfl_xor(v, 8);
        if (ml == 0) zbuf[wv][mt * 16 + quad * 4 + rr][p] = v;
      }
  }
  __syncthreads();
  for (int i = t; i < 384; i += 256) {
    int r = i / 6, p = i % 6;
    long grow = rowBase + r;
    if (grow < NN) {
      float v = zbuf[0][r][p] + zbuf[1][r][p] + zbuf[2][r][p] + zbuf[3][r][p];
      if (p < 4) z2[grow * 4 + p] = v;
      else       out[grow * 2 + (p - 4)] = v + b2[p - 4];
    }
  }
}

// 4 lanes per node: lane sub handles every-4th edge; reduce over sub.
__global__ void gather2(const float* __restrict__ z2, const int* __restrict__ off,
                        const int* __restrict__ srcs, float* __restrict__ out) {
  int tid = blockIdx.x * blockDim.x + threadIdx.x;
  int n = tid >> 2;
  if (n >= NN) return;
  int sub = tid & 3;
  int e0 = off[2 * n];
  int e1 = off[2 * n + 1];
  int e2 = off[2 * n + 2];
  float o0 = 0.f, o1 = 0.f;
  for (int e = e0 + sub; e < e1; e += 4) {
    float2 v = *(const float2*)(z2 + (long)srcs[e] * 4);
    o0 += v.x; o1 += v.y;
  }
  for (int e = e1 + sub; e < e2; e += 4) {
    float2 v = *(const float2*)(z2 + (long)srcs[e] * 4 + 2);
    o0 += v.x; o1 += v.y;
  }
  o0 += __shfl_xor(o0, 1); o1 += __shfl_xor(o1, 1);
  o0 += __shfl_xor(o0, 2); o1 += __shfl_xor(o1, 2);
  if (sub == 0) {
    out[n * 2 + 0] += o0;
    out[n * 2 + 1] += o1;
  }
}

extern "C" void kernel_launch(void* const* d_in, const int* in_sizes, int n_in,
                              void* d_out, int out_size, void* d_ws, size_t ws_size,
                              hipStream_t stream) {
  const float* x   = (const float*)d_in[0];
  const int*   ei  = (const int*)d_in[1];
  const int*   et  = (const int*)d_in[2];
  const float* w1s = (const float*)d_in[3];
  const float* w1r = (const float*)d_in[4];
  const float* b1  = (const float*)d_in[5];
  const float* w2s = (const float*)d_in[6];
  const float* w2r = (const float*)d_in[7];
  const float* b2  = (const float*)d_in[8];
  float* out = (float*)d_out;
  const int E = in_sizes[2];
  const int* src = ei;
  const int* dst = ei + E;

  f16*   aggh = (f16*)d_ws;                      // NN*256 f16   (51.2 MB)
  f16*   xh   = aggh + (size_t)NN * 256;         // NN*128 f16   (25.6 MB)
  f16*   w1t  = xh + (size_t)NN * 128;           // 12*256*32 f16 (0.2 MB)
  float* z2   = (float*)(w1t + 12 * 256 * 32);   // NN*4 f32     (1.6 MB)
  int2*  ebuf = (int2*)(z2 + (size_t)NN * 4);    // E int2       (12.8 MB)
  int*   srcs = (int*)(ebuf + E);                // E int        (6.4 MB)
  int*   off  = srcs + E;                        // NR+1 int     (0.8 MB)
  int*   gcnt = off + NR + 1;                    // NB int
  int*   bstart = gcnt + NB;                     // NB+1 int
  int*   gbase  = bstart + NB + 1;               // NB int

  int nblk = (E + CHUNK - 1) / CHUNK;
  zero_small<<<1, 512, 0, stream>>>(gcnt);
  bucketA<<<nblk, 256, 0, stream>>>(dst, et, gcnt, E);
  bscan<<<1, 512, 0, stream>>>(gcnt, bstart, gbase);
  bucketB<<<nblk, 256, 0, stream>>>(src, dst, et, gbase, ebuf, E);
  bucketC<<<NB, 256, 0, stream>>>(ebuf, bstart, off, srcs);

  int n4 = NN * 128 / 4;
  cvt_x<<<(n4 + 255) / 256, 256, 0, stream>>>((const float4*)x, xh, n4);
  cvt_w<<<(12 * 256 * 32 + 255) / 256, 256, 0, stream>>>(w1s, w1r, w1t);

  aggregate<<<(NN * 64 + 255) / 256, 256, 0, stream>>>(xh, off, srcs, aggh);

  gemm_mfma<<<(NN + 63) / 64, 256, 0, stream>>>(xh, aggh, w1t, b1, w2s, w2r, b2,
                                                z2, out);

  gather2<<<(NN * 4 + 255) / 256, 256, 0, stream>>>(z2, off, srcs, out);
}